// Round 8
// baseline (151.665 us; speedup 1.0000x reference)
//
#include <hip/hip_runtime.h>
#include <math.h>

#define NB 8
#define NA 512
#define NN 64
#define ND 128
#define NF 128
#define NG 25
#define NGA 512
#define TABN 1024

typedef __attribute__((ext_vector_type(8))) short bf16x8;
typedef __attribute__((ext_vector_type(4))) float f32x4;

__device__ __forceinline__ float sspf(float v) {
  return fmaxf(v, 0.0f) + __logf(1.0f + __expf(-fabsf(v))) - 0.6931471805599453f;
}

__device__ __forceinline__ short f2bf(float x) {
  union { float f; unsigned u; } v; v.f = x;
  unsigned r = v.u + 0x7fffu + ((v.u >> 16) & 1u);   // RNE
  return (short)(r >> 16);
}

#if defined(__has_builtin)
#if __has_builtin(__builtin_amdgcn_cvt_pk_bf16_f32)
#define HAS_PKBF 1
#endif
#endif

__device__ __forceinline__ unsigned pk2bf(float a, float b) {
#ifdef HAS_PKBF
  typedef __attribute__((ext_vector_type(2))) __bf16 v2bf;
  union { v2bf v; unsigned u; } c;
  c.v = __builtin_amdgcn_cvt_pk_bf16_f32(a, b);
  return c.u;
#else
  union { float f; unsigned u; } x, y; x.f = a; y.f = b;
  const unsigned ra = (x.u + 0x7fffu + ((x.u >> 16) & 1u)) >> 16;
  const unsigned rb = (y.u + 0x7fffu + ((y.u >> 16) & 1u)) & 0xffff0000u;
  return ra | rb;
#endif
}

__device__ __forceinline__ float bf2f(unsigned short us) {
  union { unsigned u; float f; } v; v.u = ((unsigned)us) << 16; return v.f;
}

__device__ __forceinline__ bf16x8 pack8(float4 a, float4 b) {
  bf16x8 r;
  unsigned* p = (unsigned*)&r;
  p[0] = pk2bf(a.x, a.y); p[1] = pk2bf(a.z, a.w);
  p[2] = pk2bf(b.x, b.y); p[3] = pk2bf(b.z, b.w);
  return r;
}

// W^T-style fragment built from row-major M[k][n]: elem i = bf16(M[k0q+i][n])
__device__ __forceinline__ bf16x8 fragT(const float* __restrict__ M, int ldn,
                                        int n, int k0q) {
  float e[8];
#pragma unroll
  for (int i = 0; i < 8; ++i) e[i] = M[(size_t)(k0q + i) * ldn + n];
  bf16x8 r; unsigned* p = (unsigned*)&r;
  p[0] = pk2bf(e[0], e[1]); p[1] = pk2bf(e[2], e[3]);
  p[2] = pk2bf(e[4], e[5]); p[3] = pk2bf(e[6], e[7]);
  return r;
}

// same but rows k >= NG read as 0 (w1 is [25][128])
__device__ __forceinline__ bf16x8 fragT25(const float* __restrict__ M,
                                          int n, int k0q) {
  float e[8];
#pragma unroll
  for (int i = 0; i < 8; ++i)
    e[i] = (k0q + i < NG) ? M[(size_t)(k0q + i) * NF + n] : 0.0f;
  bf16x8 r; unsigned* p = (unsigned*)&r;
  p[0] = pk2bf(e[0], e[1]); p[1] = pk2bf(e[2], e[3]);
  p[2] = pk2bf(e[4], e[5]); p[3] = pk2bf(e[6], e[7]);
  return r;
}

// ---- k_prep1 grid layout (all blocks independent) ----
#define B_TT 48                  // in2f transpose: 3 x 16 tiles
#define B_AT (B_TT + 192)        // aw transpose: 3 x 64 tiles           -> 240
#define B_PF (B_AT + 24)         // W12 fuse + b12                       -> 264
#define B_TAB (B_PF + 192)       // filter table direct: 3 x 64          -> 456
#define P1_TOT (B_TAB + 1024)    // neighbor compaction: 4096/4          -> 1480

// ====== prep1: transposes, W12, filter table, neighbor compaction =========
__global__ __launch_bounds__(256) void k_prep1(
    const float* __restrict__ fw1, const float* __restrict__ fb1,
    const float* __restrict__ fw2, const float* __restrict__ fb2,
    const float* __restrict__ in2f, const float* __restrict__ aw,
    const float* __restrict__ f2o, const float* __restrict__ f2ob,
    const float* __restrict__ dw, const float* __restrict__ db,
    const float* __restrict__ pos, const int* __restrict__ nbr,
    const int* __restrict__ nmask,
    short* __restrict__ in2fT, short* __restrict__ awT,
    short* __restrict__ W12T, float* __restrict__ b12,
    float* __restrict__ Ttab, int4* __restrict__ ent,
    int* __restrict__ nvArr) {
  __shared__ alignas(16) short sTile[32][33];
  __shared__ alignas(16) short sH[16 * 136];
  __shared__ alignas(16) int4 sCmp[4][NN];
  const int bx = blockIdx.x;
  const int t = threadIdx.x;
  const int lane = t & 63, wave = t >> 6;
  const int lanelo = lane & 15, quad = lane >> 4;
  const int wbase = wave << 5;

  if (bx < B_AT) {
    // ---- tiled bf16 transposes: in2f -> in2fT, aw -> awT ----
    const float* src; short* dst; int tk0, tn0, stride;
    if (bx < B_TT) {
      const int l = bx >> 4, tile = bx & 15;
      src = in2f + (size_t)l * 16384;
      dst = in2fT + (size_t)l * 16384;
      tk0 = (tile >> 2) << 5; tn0 = (tile & 3) << 5; stride = 128;
    } else {
      const int ab = bx - B_TT;
      const int l = ab >> 6, tile = ab & 63;
      src = aw + (size_t)l * 65536;
      dst = awT + (size_t)l * 65536;
      tk0 = (tile >> 2) << 5; tn0 = (tile & 3) << 5; stride = 512;
    }
    const int tr = t >> 3, tc4 = (t & 7) << 2;
    const float4 v = *(const float4*)(src + (size_t)(tk0 + tr) * 128 + tn0 + tc4);
    sTile[tr][tc4] = f2bf(v.x); sTile[tr][tc4 + 1] = f2bf(v.y);
    sTile[tr][tc4 + 2] = f2bf(v.z); sTile[tr][tc4 + 3] = f2bf(v.w);
    __syncthreads();
    short o[4];
#pragma unroll
    for (int j = 0; j < 4; ++j) o[j] = sTile[tc4 + j][tr];
    uint2 pk;
    pk.x = ((unsigned)(unsigned short)o[0]) | (((unsigned)(unsigned short)o[1]) << 16);
    pk.y = ((unsigned)(unsigned short)o[2]) | (((unsigned)(unsigned short)o[3]) << 16);
    *(uint2*)(dst + (size_t)(tn0 + tr) * stride + tk0 + tc4) = pk;
    return;
  }
  if (bx < B_PF) {
    // ---- W12 = f2o@dw (bf16 [j][i]), b12 = f2ob@dw + db ----
    const int fb = bx - B_AT;
    const int l = fb >> 3, xi = fb & 7;
    const int i = (xi << 4) + lanelo;
    const float* f2o_l = f2o + (size_t)l * 16384;
    const float* dw_l = dw + (size_t)l * 16384;
    short* W12T_l = W12T + (size_t)l * 16384;
    f32x4 c[2] = {{0.f, 0.f, 0.f, 0.f}, {0.f, 0.f, 0.f, 0.f}};
#pragma unroll
    for (int kt = 0; kt < 4; ++kt) {
      const int k0 = kt * 32 + quad * 8;
      const bf16x8 b = pack8(*(const float4*)(f2o_l + (size_t)i * 128 + k0),
                             *(const float4*)(f2o_l + (size_t)i * 128 + k0 + 4));
#pragma unroll
      for (int ct = 0; ct < 2; ++ct) {
        const bf16x8 a = fragT(dw_l, 128, wbase + ct * 16 + lanelo, k0);
        c[ct] = __builtin_amdgcn_mfma_f32_16x16x32_bf16(a, b, c[ct], 0, 0, 0);
      }
    }
#pragma unroll
    for (int ct = 0; ct < 2; ++ct)
#pragma unroll
      for (int reg = 0; reg < 4; ++reg) {
        const int j = wbase + ct * 16 + quad * 4 + reg;
        W12T_l[(size_t)j * 128 + i] = f2bf(c[ct][reg]);
      }
    if (xi == 0 && t < 128) {
      float acc = db[(size_t)l * 128 + t];
      for (int k = 0; k < 128; ++k)
        acc += f2ob[(size_t)l * 128 + k] * dw_l[(size_t)k * 128 + t];
      b12[(size_t)l * 128 + t] = acc;
    }
    return;
  }
  if (bx < B_TAB) {
    // ---- filter table via MFMA, direct fp32 weight fragments ----
    const int tb = bx - B_PF;                  // 0..191
    const int l = tb >> 6;
    const int chunk = tb & 63;                 // 16-row chunk
    const float* fw1_l = fw1 + (size_t)l * NG * NF;
    const float* fw2_l = fw2 + (size_t)l * 16384;
    const float* b1 = fb1 + (size_t)l * NF;
    const float* b2 = fb2 + (size_t)l * NF;

    float4 b1v[2];
    float b2r[2];
#pragma unroll
    for (int ct = 0; ct < 2; ++ct) {
      b1v[ct] = *(const float4*)(b1 + wbase + ct * 16 + quad * 4);
      b2r[ct] = b2[wbase + ct * 16 + lanelo];
    }

    const float stepg = 3.8f / 24.0f;
    const float coef = -0.5f / (stepg * stepg);
    const float rv = (float)(chunk * 16 + lanelo) * (5.0f / 1023.0f);
    bf16x8 gb;
    {
      float e[8];
#pragma unroll
      for (int i = 0; i < 8; ++i) {
        const int g = quad * 8 + i;
        const float d = rv - (1.2f + stepg * (float)g);
        e[i] = (g < NG) ? __expf(coef * d * d) : 0.0f;
      }
      unsigned* gp = (unsigned*)&gb;
      gp[0] = pk2bf(e[0], e[1]); gp[1] = pk2bf(e[2], e[3]);
      gp[2] = pk2bf(e[4], e[5]); gp[3] = pk2bf(e[6], e[7]);
    }
    // phase 1: h = ssp(gauss @ w1 + b1) -> sH[row][f]
#pragma unroll
    for (int ct = 0; ct < 2; ++ct) {
      const bf16x8 a = fragT25(fw1_l, wbase + ct * 16 + lanelo, quad * 8);
      f32x4 c = {0.f, 0.f, 0.f, 0.f};
      c = __builtin_amdgcn_mfma_f32_16x16x32_bf16(a, gb, c, 0, 0, 0);
      const int f0 = wbase + ct * 16 + quad * 4;
      uint2 pk;
      pk.x = pk2bf(sspf(c[0] + b1v[ct].x), sspf(c[1] + b1v[ct].y));
      pk.y = pk2bf(sspf(c[2] + b1v[ct].z), sspf(c[3] + b1v[ct].w));
      *(uint2*)(sH + lanelo * 136 + f0) = pk;
    }
    __syncthreads();
    // phase 2: T = h @ w2 + b2 -> Ttab fp32
    f32x4 acc[2];
    acc[0] = (f32x4){b2r[0], b2r[0], b2r[0], b2r[0]};
    acc[1] = (f32x4){b2r[1], b2r[1], b2r[1], b2r[1]};
#pragma unroll
    for (int kt = 0; kt < 4; ++kt) {
      const bf16x8 ah = *(const bf16x8*)(sH + lanelo * 136 + kt * 32 + quad * 8);
#pragma unroll
      for (int ct = 0; ct < 2; ++ct) {
        const bf16x8 a = fragT(fw2_l, 128, wbase + ct * 16 + lanelo, kt * 32 + quad * 8);
        acc[ct] = __builtin_amdgcn_mfma_f32_16x16x32_bf16(ah, a, acc[ct], 0, 0, 0);
      }
    }
#pragma unroll
    for (int ct = 0; ct < 2; ++ct)
#pragma unroll
      for (int reg = 0; reg < 4; ++reg) {
        const int rrow = chunk * 16 + quad * 4 + reg;
        const int f = wbase + ct * 16 + lanelo;
        Ttab[((size_t)l * TABN + rrow) * NF + f] = acc[ct][reg];
      }
    return;
  }
  // ---- neighbor compaction: layer-invariant lerp entries ----
  {
    const int ga = (bx - B_TAB) * 4 + wave;    // 4 atoms/block, 1 per wave
    const int b0 = ga & ~(NA - 1);
    const int nj = nbr[(size_t)ga * NN + lane];
    const int mk = nmask[(size_t)ga * NN + lane];
    const float px = pos[(size_t)ga * 3];
    const float py = pos[(size_t)ga * 3 + 1];
    const float pz = pos[(size_t)ga * 3 + 2];
    const float* pj = pos + (size_t)(b0 + nj) * 3;
    const float dx = pj[0] - px, dy = pj[1] - py, dz = pj[2] - pz;
    const float r = sqrtf(dx * dx + dy * dy + dz * dz + 1e-12f);
    const bool valid = (r <= 5.0f) && (mk != 0);
    const unsigned long long m = __ballot(valid);
    const int posc = __popcll(m & ((1ull << lane) - 1ull));
    const float tt = r * ((float)(TABN - 1) / 5.0f);
    int k0 = (int)tt; if (k0 > TABN - 2) k0 = TABN - 2;
    const float fr = tt - (float)k0;
    sCmp[wave][lane] = make_int4(0, b0 * NF, 0, 0);          // zero entry
    if (valid)
      sCmp[wave][posc] = make_int4(k0 * NF, (b0 + nj) * NF,
                                   __float_as_int(1.0f - fr), __float_as_int(fr));
    // wave-private rows; in-wave LDS ordering suffices (no barrier)
    ent[(size_t)ga * NN + lane] = sCmp[wave][lane];
    if (lane == 0) nvArr[ga] = (int)__popcll(m);
  }
}

// ======= prep2: y0 = bf16(emb[zn] @ in2f[0]) + x init (256 blocks) =========
__global__ __launch_bounds__(256) void k_prep2(
    const float* __restrict__ emb, const int* __restrict__ zn,
    const short* __restrict__ in2fT,
    float* __restrict__ x, short* __restrict__ yB) {
  const int bx = blockIdx.x;
  const int t = threadIdx.x;
  const int lane = t & 63, wave = t >> 6;
  const int lanelo = lane & 15, quad = lane >> 4;
  const int wbase = wave << 5;

  const int row = (bx << 4) + lanelo;
  const float* erow = emb + (size_t)zn[row] * ND;
  f32x4 c[2] = {{0.f, 0.f, 0.f, 0.f}, {0.f, 0.f, 0.f, 0.f}};
#pragma unroll
  for (int kt = 0; kt < 4; ++kt) {
    const int k0 = kt * 32 + quad * 8;
    const float4 e0 = *(const float4*)(erow + k0);
    const float4 e1 = *(const float4*)(erow + k0 + 4);
    if (wave == 0) {
      *(float4*)(x + (size_t)row * ND + k0) = e0;
      *(float4*)(x + (size_t)row * ND + k0 + 4) = e1;
    }
    const bf16x8 b = pack8(e0, e1);
#pragma unroll
    for (int ct = 0; ct < 2; ++ct) {
      const bf16x8 a = *(const bf16x8*)(in2fT + (size_t)(wbase + ct * 16 + lanelo) * 128 + k0);
      c[ct] = __builtin_amdgcn_mfma_f32_16x16x32_bf16(a, b, c[ct], 0, 0, 0);
    }
  }
#pragma unroll
  for (int ct = 0; ct < 2; ++ct) {
    const int c0 = wbase + ct * 16 + quad * 4;
    uint2 pk; pk.x = pk2bf(c[ct][0], c[ct][1]); pk.y = pk2bf(c[ct][2], c[ct][3]);
    *(uint2*)(yB + (size_t)row * 128 + c0) = pk;
  }
}

// ====== fused layer: conv + vang-in-register + interaction update ==========
// 512 blocks x 512 threads; block owns 8 atoms, one per wave. Conv: precompacted
// table lerp. vang = Gi@aw accumulates into the SAME MFMA accumulator as
// GEMM1 (identical D-layout: col=atom, row=f) from LDS-staged bf16 Gi rows.
__global__ __launch_bounds__(512, 4) void k_layer(
    const short* __restrict__ yIn, const float* __restrict__ Tt,
    const float* __restrict__ Gi, const short* __restrict__ awTl,
    float* __restrict__ x,
    const short* __restrict__ W12Tl, const float* __restrict__ b12l,
    const short* __restrict__ in2fTn, short* __restrict__ yOut,
    const int4* __restrict__ ent, const int* __restrict__ nvArr) {
  __shared__ alignas(16) int4 sEnt[8][NN];
  __shared__ alignas(16) float sAgg[16][136];
  __shared__ alignas(16) short sT[16 * 136];
  __shared__ alignas(16) short sGi[8][520];   // 8 atoms x 512 bf16 (+pad)

  const int t = threadIdx.x;
  const int lane = t & 63;
  const int wave = t >> 6;            // 0..7 = atom slot
  const int lanelo = lane & 15;
  const int quad = lane >> 4;
  const int ga0 = blockIdx.x << 3;

  // ---- stage Gi rows for own 8 atoms (coalesced fp32 -> bf16) ----
  {
    const int r = t >> 6, cc = (t & 63) << 3;       // row 0..7, col 0..504
    const float* g = Gi + (size_t)(ga0 + r) * NGA + cc;
    const bf16x8 v = pack8(*(const float4*)g, *(const float4*)(g + 4));
    *(bf16x8*)(&sGi[r][cc]) = v;
  }

  // ---- coalesced entry preload (wave-private rows: no barrier needed) ----
  sEnt[wave][lane] = ent[(size_t)(ga0 + wave) * NN + lane];
  const int nv = nvArr[ga0 + wave];

  const unsigned short* yu = (const unsigned short*)yIn;
  float acc0 = 0.f, acc1 = 0.f;
  const int ntc = (nv + 3) & ~3;
  for (int c = 0; c < ntc; c += 4) {
#pragma unroll
    for (int u = 0; u < 4; ++u) {
      const int4 e = sEnt[wave][c + u];
      const float w0 = __int_as_float(e.z), w1 = __int_as_float(e.w);
      const float t0a = Tt[e.x + lane];
      const float t0b = Tt[e.x + lane + 64];
      const float t1a = Tt[e.x + NF + lane];
      const float t1b = Tt[e.x + NF + lane + 64];
      const float wva = fmaf(w0, t0a, w1 * t1a);
      const float wvb = fmaf(w0, t0b, w1 * t1b);
      acc0 = fmaf(wva, bf2f(yu[e.y + lane]), acc0);
      acc1 = fmaf(wvb, bf2f(yu[e.y + lane + 64]), acc1);
    }
  }
  sAgg[wave][lane] = acc0;
  sAgg[wave][lane + 64] = acc1;
  __syncthreads();   // covers sAgg and sGi

  // ---- GEMM1 (W12 @ agg) + vang (awT @ Gi) into ONE accumulator ----
  f32x4 c2 = {0.f, 0.f, 0.f, 0.f};
#pragma unroll
  for (int kt = 0; kt < 4; ++kt) {
    const float* ar = &sAgg[lanelo][kt * 32 + quad * 8];
    const bf16x8 b = pack8(*(const float4*)ar, *(const float4*)(ar + 4));
    const bf16x8 a = *(const bf16x8*)(W12Tl + ((wave << 4) + lanelo) * 128 + kt * 32 + quad * 8);
    c2 = __builtin_amdgcn_mfma_f32_16x16x32_bf16(a, b, c2, 0, 0, 0);
  }
#pragma unroll 4
  for (int kt = 0; kt < 16; ++kt) {
    const int k0 = kt * 32 + quad * 8;
    const bf16x8 a = *(const bf16x8*)(awTl + (size_t)((wave << 4) + lanelo) * 512 + k0);
    const bf16x8 b = *(const bf16x8*)(&sGi[lanelo & 7][k0]);
    c2 = __builtin_amdgcn_mfma_f32_16x16x32_bf16(a, b, c2, 0, 0, 0);
  }

  const int c0 = (wave << 4) + quad * 4;
  const int row = ga0 + lanelo;
  if (lanelo < 8) {
    const float4 dv = *(const float4*)(b12l + c0);
    float* xp = x + (size_t)row * 128 + c0;
    const float4 xv = *(const float4*)xp;
    float4 xo;
    xo.x = xv.x + sspf(c2[0] + dv.x);
    xo.y = xv.y + sspf(c2[1] + dv.y);
    xo.z = xv.z + sspf(c2[2] + dv.z);
    xo.w = xv.w + sspf(c2[3] + dv.w);
    *(float4*)xp = xo;
    if (in2fTn != nullptr) {
      uint2 pk; pk.x = pk2bf(xo.x, xo.y); pk.y = pk2bf(xo.z, xo.w);
      *(uint2*)(sT + lanelo * 136 + c0) = pk;
    }
  }
  if (in2fTn == nullptr) return;
  __syncthreads();

  // ---- GEMM2: y_next = in2f[l+1] @ x_new ----
  f32x4 c3 = {0.f, 0.f, 0.f, 0.f};
#pragma unroll
  for (int kt = 0; kt < 4; ++kt) {
    const bf16x8 b = *(const bf16x8*)(sT + lanelo * 136 + kt * 32 + quad * 8);
    const bf16x8 a = *(const bf16x8*)(in2fTn + ((wave << 4) + lanelo) * 128 + kt * 32 + quad * 8);
    c3 = __builtin_amdgcn_mfma_f32_16x16x32_bf16(a, b, c3, 0, 0, 0);
  }
  if (lanelo < 8) {
    uint2 pk; pk.x = pk2bf(c3[0], c3[1]); pk.y = pk2bf(c3[2], c3[3]);
    *(uint2*)(yOut + (size_t)row * 128 + c0) = pk;
  }
}

extern "C" void kernel_launch(void* const* d_in, const int* in_sizes, int n_in,
                              void* d_out, int out_size, void* d_ws, size_t ws_size,
                              hipStream_t stream) {
  (void)in_sizes; (void)n_in; (void)out_size; (void)ws_size;
  const int* zn = (const int*)d_in[0];
  const float* pos = (const float*)d_in[1];
  const int* nbr = (const int*)d_in[2];
  const int* nmask = (const int*)d_in[3];
  const float* Gi = (const float*)d_in[4];
  const float* emb = (const float*)d_in[5];
  const float* fw1 = (const float*)d_in[6];
  const float* fb1 = (const float*)d_in[7];
  const float* fw2 = (const float*)d_in[8];
  const float* fb2 = (const float*)d_in[9];
  const float* in2f = (const float*)d_in[10];
  const float* f2o = (const float*)d_in[11];
  const float* f2ob = (const float*)d_in[12];
  const float* dwp = (const float*)d_in[13];
  const float* dbp = (const float*)d_in[14];
  const float* awp = (const float*)d_in[15];

  float* x = (float*)d_out;                              // [B,A,D] fp32
  float* b12 = (float*)d_ws;                             // [3][128] fp32
  float* Ttab = b12 + 3 * 128;                           // [3][1024][128] fp32
  short* yA = (short*)(Ttab + (size_t)3 * TABN * NF);    // y buf 0
  short* yBb = yA + (size_t)NB * NA * NF;                // y buf 1
  short* in2fT = yBb + (size_t)NB * NA * NF;             // [3][128][128]
  short* W12T = in2fT + (size_t)3 * 128 * 128;           // [3][128][128]
  short* awT = W12T + (size_t)3 * 128 * 128;             // [3][128][512]
  int4* ent = (int4*)(awT + (size_t)3 * 128 * 512);      // [B*A][64]
  int* nvArr = (int*)(ent + (size_t)NB * NA * NN);       // [B*A]

  k_prep1<<<P1_TOT, 256, 0, stream>>>(
      fw1, fb1, fw2, fb2, in2f, awp, f2o, f2ob, dwp, dbp,
      pos, nbr, nmask,
      in2fT, awT, W12T, b12, Ttab, ent, nvArr);
  k_prep2<<<NB * NA / 16, 256, 0, stream>>>(
      emb, zn, in2fT, x, yA);

  short* yin = yA;
  short* yout = yBb;
  for (int l = 0; l < 3; ++l) {
    k_layer<<<NB * NA / 8, 512, 0, stream>>>(yin,
        Ttab + (size_t)l * TABN * NF,
        Gi, awT + (size_t)l * 65536,
        x, W12T + (size_t)l * 16384, b12 + (size_t)l * 128,
        (l < 2) ? (in2fT + (size_t)(l + 1) * 16384) : nullptr, yout,
        ent, nvArr);
    short* tmp = yin; yin = yout; yout = tmp;
  }
}

// Round 9
// 148.529 us; speedup vs baseline: 1.0211x; 1.0211x over previous
//
#include <hip/hip_runtime.h>
#include <math.h>

#define NB 8
#define NA 512
#define NN 64
#define ND 128
#define NF 128
#define NG 25
#define NGA 512
#define TABN 1024

typedef __attribute__((ext_vector_type(8))) short bf16x8;
typedef __attribute__((ext_vector_type(4))) float f32x4;

__device__ __forceinline__ float sspf(float v) {
  return fmaxf(v, 0.0f) + __logf(1.0f + __expf(-fabsf(v))) - 0.6931471805599453f;
}

__device__ __forceinline__ short f2bf(float x) {
  union { float f; unsigned u; } v; v.f = x;
  unsigned r = v.u + 0x7fffu + ((v.u >> 16) & 1u);   // RNE
  return (short)(r >> 16);
}

#if defined(__has_builtin)
#if __has_builtin(__builtin_amdgcn_cvt_pk_bf16_f32)
#define HAS_PKBF 1
#endif
#endif

__device__ __forceinline__ unsigned pk2bf(float a, float b) {
#ifdef HAS_PKBF
  typedef __attribute__((ext_vector_type(2))) __bf16 v2bf;
  union { v2bf v; unsigned u; } c;
  c.v = __builtin_amdgcn_cvt_pk_bf16_f32(a, b);
  return c.u;
#else
  union { float f; unsigned u; } x, y; x.f = a; y.f = b;
  const unsigned ra = (x.u + 0x7fffu + ((x.u >> 16) & 1u)) >> 16;
  const unsigned rb = (y.u + 0x7fffu + ((y.u >> 16) & 1u)) & 0xffff0000u;
  return ra | rb;
#endif
}

__device__ __forceinline__ float bf2f(unsigned short us) {
  union { unsigned u; float f; } v; v.u = ((unsigned)us) << 16; return v.f;
}

__device__ __forceinline__ bf16x8 pack8(float4 a, float4 b) {
  bf16x8 r;
  unsigned* p = (unsigned*)&r;
  p[0] = pk2bf(a.x, a.y); p[1] = pk2bf(a.z, a.w);
  p[2] = pk2bf(b.x, b.y); p[3] = pk2bf(b.z, b.w);
  return r;
}

// W^T-style fragment built from row-major M[k][n]: elem i = bf16(M[k0q+i][n])
__device__ __forceinline__ bf16x8 fragT(const float* __restrict__ M, int ldn,
                                        int n, int k0q) {
  float e[8];
#pragma unroll
  for (int i = 0; i < 8; ++i) e[i] = M[(size_t)(k0q + i) * ldn + n];
  bf16x8 r; unsigned* p = (unsigned*)&r;
  p[0] = pk2bf(e[0], e[1]); p[1] = pk2bf(e[2], e[3]);
  p[2] = pk2bf(e[4], e[5]); p[3] = pk2bf(e[6], e[7]);
  return r;
}

// same but rows k >= NG read as 0 (w1 is [25][128])
__device__ __forceinline__ bf16x8 fragT25(const float* __restrict__ M,
                                          int n, int k0q) {
  float e[8];
#pragma unroll
  for (int i = 0; i < 8; ++i)
    e[i] = (k0q + i < NG) ? M[(size_t)(k0q + i) * NF + n] : 0.0f;
  bf16x8 r; unsigned* p = (unsigned*)&r;
  p[0] = pk2bf(e[0], e[1]); p[1] = pk2bf(e[2], e[3]);
  p[2] = pk2bf(e[4], e[5]); p[3] = pk2bf(e[6], e[7]);
  return r;
}

// ---- single prep kernel grid layout (all blocks independent) ----
#define B_TAB 192                 // filter table: 3 layers x 64 chunks
#define B_AT (B_TAB + 192)        // aw transpose: 3 x 64 tiles          -> 384
#define B_PF (B_AT + 24)          // W12 fuse + b12                      -> 408
#define B_TT (B_PF + 32)          // in2f transpose, layers 1,2 only     -> 440
#define B_Y0 (B_TT + 256)         // y0 + x init (direct fp32 frags)     -> 696
#define P_TOT (B_Y0 + 256)        // neighbor compaction: 16 atoms/block -> 952

// ====== prep: table, transposes, W12, y0/x, neighbor compaction ===========
__global__ __launch_bounds__(256) void k_prep(
    const float* __restrict__ fw1, const float* __restrict__ fb1,
    const float* __restrict__ fw2, const float* __restrict__ fb2,
    const float* __restrict__ in2f, const float* __restrict__ aw,
    const float* __restrict__ f2o, const float* __restrict__ f2ob,
    const float* __restrict__ dw, const float* __restrict__ db,
    const float* __restrict__ pos, const int* __restrict__ nbr,
    const int* __restrict__ nmask,
    const float* __restrict__ emb, const int* __restrict__ zn,
    short* __restrict__ in2fT, short* __restrict__ awT,
    short* __restrict__ W12T, float* __restrict__ b12,
    float* __restrict__ Ttab, int4* __restrict__ ent,
    int* __restrict__ nvArr, float* __restrict__ x,
    short* __restrict__ yB) {
  __shared__ alignas(16) short sTile[32][33];
  __shared__ alignas(16) short sH[16 * 136];
  __shared__ alignas(16) int4 sCmp[4][NN];
  const int bx = blockIdx.x;
  const int t = threadIdx.x;
  const int lane = t & 63, wave = t >> 6;
  const int lanelo = lane & 15, quad = lane >> 4;
  const int wbase = wave << 5;

  if (bx < B_TAB) {
    // ---- filter table via MFMA, direct fp32 weight fragments ----
    const int l = bx >> 6;
    const int chunk = bx & 63;                 // 16-row chunk
    const float* fw1_l = fw1 + (size_t)l * NG * NF;
    const float* fw2_l = fw2 + (size_t)l * 16384;
    const float* b1 = fb1 + (size_t)l * NF;
    const float* b2 = fb2 + (size_t)l * NF;

    float4 b1v[2];
    float b2r[2];
#pragma unroll
    for (int ct = 0; ct < 2; ++ct) {
      b1v[ct] = *(const float4*)(b1 + wbase + ct * 16 + quad * 4);
      b2r[ct] = b2[wbase + ct * 16 + lanelo];
    }

    const float stepg = 3.8f / 24.0f;
    const float coef = -0.5f / (stepg * stepg);
    const float rv = (float)(chunk * 16 + lanelo) * (5.0f / 1023.0f);
    bf16x8 gb;
    {
      float e[8];
#pragma unroll
      for (int i = 0; i < 8; ++i) {
        const int g = quad * 8 + i;
        const float d = rv - (1.2f + stepg * (float)g);
        e[i] = (g < NG) ? __expf(coef * d * d) : 0.0f;
      }
      unsigned* gp = (unsigned*)&gb;
      gp[0] = pk2bf(e[0], e[1]); gp[1] = pk2bf(e[2], e[3]);
      gp[2] = pk2bf(e[4], e[5]); gp[3] = pk2bf(e[6], e[7]);
    }
    // phase 1: h = ssp(gauss @ w1 + b1) -> sH[row][f]
#pragma unroll
    for (int ct = 0; ct < 2; ++ct) {
      const bf16x8 a = fragT25(fw1_l, wbase + ct * 16 + lanelo, quad * 8);
      f32x4 c = {0.f, 0.f, 0.f, 0.f};
      c = __builtin_amdgcn_mfma_f32_16x16x32_bf16(a, gb, c, 0, 0, 0);
      const int f0 = wbase + ct * 16 + quad * 4;
      uint2 pk;
      pk.x = pk2bf(sspf(c[0] + b1v[ct].x), sspf(c[1] + b1v[ct].y));
      pk.y = pk2bf(sspf(c[2] + b1v[ct].z), sspf(c[3] + b1v[ct].w));
      *(uint2*)(sH + lanelo * 136 + f0) = pk;
    }
    __syncthreads();
    // phase 2: T = h @ w2 + b2 -> Ttab fp32
    f32x4 acc[2];
    acc[0] = (f32x4){b2r[0], b2r[0], b2r[0], b2r[0]};
    acc[1] = (f32x4){b2r[1], b2r[1], b2r[1], b2r[1]};
#pragma unroll
    for (int kt = 0; kt < 4; ++kt) {
      const bf16x8 ah = *(const bf16x8*)(sH + lanelo * 136 + kt * 32 + quad * 8);
#pragma unroll
      for (int ct = 0; ct < 2; ++ct) {
        const bf16x8 a = fragT(fw2_l, 128, wbase + ct * 16 + lanelo, kt * 32 + quad * 8);
        acc[ct] = __builtin_amdgcn_mfma_f32_16x16x32_bf16(ah, a, acc[ct], 0, 0, 0);
      }
    }
#pragma unroll
    for (int ct = 0; ct < 2; ++ct)
#pragma unroll
      for (int reg = 0; reg < 4; ++reg) {
        const int rrow = chunk * 16 + quad * 4 + reg;
        const int f = wbase + ct * 16 + lanelo;
        Ttab[((size_t)l * TABN + rrow) * NF + f] = acc[ct][reg];
      }
    return;
  }
  if (bx < B_PF) {
    if (bx < B_AT) {
      // ---- aw transpose: [512][128] fp32 -> awT [128][512] bf16 ----
      const int ab = bx - B_TAB;
      const int l = ab >> 6, tile = ab & 63;
      const int tk0 = (tile >> 2) << 5, tn0 = (tile & 3) << 5;
      const float* src = aw + (size_t)l * 65536;
      short* dst = awT + (size_t)l * 65536;
      const int tr = t >> 3, tc4 = (t & 7) << 2;
      const float4 v = *(const float4*)(src + (size_t)(tk0 + tr) * 128 + tn0 + tc4);
      sTile[tr][tc4] = f2bf(v.x); sTile[tr][tc4 + 1] = f2bf(v.y);
      sTile[tr][tc4 + 2] = f2bf(v.z); sTile[tr][tc4 + 3] = f2bf(v.w);
      __syncthreads();
      short o[4];
#pragma unroll
      for (int j = 0; j < 4; ++j) o[j] = sTile[tc4 + j][tr];
      uint2 pk;
      pk.x = ((unsigned)(unsigned short)o[0]) | (((unsigned)(unsigned short)o[1]) << 16);
      pk.y = ((unsigned)(unsigned short)o[2]) | (((unsigned)(unsigned short)o[3]) << 16);
      *(uint2*)(dst + (size_t)(tn0 + tr) * 512 + tk0 + tc4) = pk;
      return;
    }
    // ---- W12 = f2o@dw (bf16 [j][i]), b12 = f2ob@dw + db ----
    const int fb = bx - B_AT;
    const int l = fb >> 3, xi = fb & 7;
    const int i = (xi << 4) + lanelo;
    const float* f2o_l = f2o + (size_t)l * 16384;
    const float* dw_l = dw + (size_t)l * 16384;
    short* W12T_l = W12T + (size_t)l * 16384;
    f32x4 c[2] = {{0.f, 0.f, 0.f, 0.f}, {0.f, 0.f, 0.f, 0.f}};
#pragma unroll
    for (int kt = 0; kt < 4; ++kt) {
      const int k0 = kt * 32 + quad * 8;
      const bf16x8 b = pack8(*(const float4*)(f2o_l + (size_t)i * 128 + k0),
                             *(const float4*)(f2o_l + (size_t)i * 128 + k0 + 4));
#pragma unroll
      for (int ct = 0; ct < 2; ++ct) {
        const bf16x8 a = fragT(dw_l, 128, wbase + ct * 16 + lanelo, k0);
        c[ct] = __builtin_amdgcn_mfma_f32_16x16x32_bf16(a, b, c[ct], 0, 0, 0);
      }
    }
#pragma unroll
    for (int ct = 0; ct < 2; ++ct)
#pragma unroll
      for (int reg = 0; reg < 4; ++reg) {
        const int j = wbase + ct * 16 + quad * 4 + reg;
        W12T_l[(size_t)j * 128 + i] = f2bf(c[ct][reg]);
      }
    if (xi == 0 && t < 128) {
      float acc = db[(size_t)l * 128 + t];
      for (int k = 0; k < 128; ++k)
        acc += f2ob[(size_t)l * 128 + k] * dw_l[(size_t)k * 128 + t];
      b12[(size_t)l * 128 + t] = acc;
    }
    return;
  }
  if (bx < B_TT) {
    // ---- in2f transpose, layers 1,2 only (layer-0 consumed directly) ----
    const int m = bx - B_PF;
    const int l = 1 + (m >> 4), tile = m & 15;
    const float* src = in2f + (size_t)l * 16384;
    short* dst = in2fT + (size_t)l * 16384;
    const int tk0 = (tile >> 2) << 5, tn0 = (tile & 3) << 5;
    const int tr = t >> 3, tc4 = (t & 7) << 2;
    const float4 v = *(const float4*)(src + (size_t)(tk0 + tr) * 128 + tn0 + tc4);
    sTile[tr][tc4] = f2bf(v.x); sTile[tr][tc4 + 1] = f2bf(v.y);
    sTile[tr][tc4 + 2] = f2bf(v.z); sTile[tr][tc4 + 3] = f2bf(v.w);
    __syncthreads();
    short o[4];
#pragma unroll
    for (int j = 0; j < 4; ++j) o[j] = sTile[tc4 + j][tr];
    uint2 pk;
    pk.x = ((unsigned)(unsigned short)o[0]) | (((unsigned)(unsigned short)o[1]) << 16);
    pk.y = ((unsigned)(unsigned short)o[2]) | (((unsigned)(unsigned short)o[3]) << 16);
    *(uint2*)(dst + (size_t)(tn0 + tr) * 128 + tk0 + tc4) = pk;
    return;
  }
  if (bx < B_Y0) {
    // ---- y0 = bf16(emb[zn] @ in2f[0]) direct from fp32; x = emb[zn] ----
    const int row = ((bx - B_TT) << 4) + lanelo;
    const float* erow = emb + (size_t)zn[row] * ND;
    f32x4 c[2] = {{0.f, 0.f, 0.f, 0.f}, {0.f, 0.f, 0.f, 0.f}};
#pragma unroll
    for (int kt = 0; kt < 4; ++kt) {
      const int k0 = kt * 32 + quad * 8;
      const float4 e0 = *(const float4*)(erow + k0);
      const float4 e1 = *(const float4*)(erow + k0 + 4);
      if (wave == 0) {
        *(float4*)(x + (size_t)row * ND + k0) = e0;
        *(float4*)(x + (size_t)row * ND + k0 + 4) = e1;
      }
      const bf16x8 b = pack8(e0, e1);
#pragma unroll
      for (int ct = 0; ct < 2; ++ct) {
        const bf16x8 a = fragT(in2f, 128, wbase + ct * 16 + lanelo, k0);
        c[ct] = __builtin_amdgcn_mfma_f32_16x16x32_bf16(a, b, c[ct], 0, 0, 0);
      }
    }
#pragma unroll
    for (int ct = 0; ct < 2; ++ct) {
      const int c0 = wbase + ct * 16 + quad * 4;
      uint2 pk; pk.x = pk2bf(c[ct][0], c[ct][1]); pk.y = pk2bf(c[ct][2], c[ct][3]);
      *(uint2*)(yB + (size_t)row * 128 + c0) = pk;
    }
    return;
  }
  // ---- neighbor compaction: 16 atoms/block, 4 per wave ----
  {
    const int gaB = (bx - B_Y0) * 16 + wave * 4;
#pragma unroll
    for (int aa = 0; aa < 4; ++aa) {
      const int ga = gaB + aa;
      const int b0 = ga & ~(NA - 1);
      const int nj = nbr[(size_t)ga * NN + lane];
      const int mk = nmask[(size_t)ga * NN + lane];
      const float px = pos[(size_t)ga * 3];
      const float py = pos[(size_t)ga * 3 + 1];
      const float pz = pos[(size_t)ga * 3 + 2];
      const float* pj = pos + (size_t)(b0 + nj) * 3;
      const float dx = pj[0] - px, dy = pj[1] - py, dz = pj[2] - pz;
      const float r = sqrtf(dx * dx + dy * dy + dz * dz + 1e-12f);
      const bool valid = (r <= 5.0f) && (mk != 0);
      const unsigned long long m = __ballot(valid);
      const int posc = __popcll(m & ((1ull << lane) - 1ull));
      const float tt = r * ((float)(TABN - 1) / 5.0f);
      int k0 = (int)tt; if (k0 > TABN - 2) k0 = TABN - 2;
      const float fr = tt - (float)k0;
      sCmp[wave][lane] = make_int4(0, b0 * NF, 0, 0);        // zero entry
      if (valid)
        sCmp[wave][posc] = make_int4(k0 * NF, (b0 + nj) * NF,
                                     __float_as_int(1.0f - fr), __float_as_int(fr));
      // wave-private rows; in-wave LDS ordering suffices (no barrier)
      ent[(size_t)ga * NN + lane] = sCmp[wave][lane];
      if (lane == 0) nvArr[ga] = (int)__popcll(m);
    }
  }
}

// ====== fused layer: conv + vang-in-register + interaction update ==========
// 512 blocks x 512 threads; block owns 8 atoms, one per wave. Conv: precompacted
// table lerp. vang = Gi@aw accumulates into the SAME MFMA accumulator as
// GEMM1 (identical D-layout: col=atom, row=f) from LDS-staged bf16 Gi rows.
__global__ __launch_bounds__(512, 4) void k_layer(
    const short* __restrict__ yIn, const float* __restrict__ Tt,
    const float* __restrict__ Gi, const short* __restrict__ awTl,
    float* __restrict__ x,
    const short* __restrict__ W12Tl, const float* __restrict__ b12l,
    const short* __restrict__ in2fTn, short* __restrict__ yOut,
    const int4* __restrict__ ent, const int* __restrict__ nvArr) {
  __shared__ alignas(16) int4 sEnt[8][NN];
  __shared__ alignas(16) float sAgg[16][136];
  __shared__ alignas(16) short sT[16 * 136];
  __shared__ alignas(16) short sGi[8][520];   // 8 atoms x 512 bf16 (+pad)

  const int t = threadIdx.x;
  const int lane = t & 63;
  const int wave = t >> 6;            // 0..7 = atom slot
  const int lanelo = lane & 15;
  const int quad = lane >> 4;
  const int ga0 = blockIdx.x << 3;

  // ---- stage Gi rows for own 8 atoms (coalesced fp32 -> bf16) ----
  {
    const int r = t >> 6, cc = (t & 63) << 3;       // row 0..7, col 0..504
    const float* g = Gi + (size_t)(ga0 + r) * NGA + cc;
    const bf16x8 v = pack8(*(const float4*)g, *(const float4*)(g + 4));
    *(bf16x8*)(&sGi[r][cc]) = v;
  }

  // ---- coalesced entry preload (wave-private rows: no barrier needed) ----
  sEnt[wave][lane] = ent[(size_t)(ga0 + wave) * NN + lane];
  const int nv = nvArr[ga0 + wave];

  const unsigned short* yu = (const unsigned short*)yIn;
  float acc0 = 0.f, acc1 = 0.f;
  const int ntc = (nv + 3) & ~3;
  for (int c = 0; c < ntc; c += 4) {
#pragma unroll
    for (int u = 0; u < 4; ++u) {
      const int4 e = sEnt[wave][c + u];
      const float w0 = __int_as_float(e.z), w1 = __int_as_float(e.w);
      const float t0a = Tt[e.x + lane];
      const float t0b = Tt[e.x + lane + 64];
      const float t1a = Tt[e.x + NF + lane];
      const float t1b = Tt[e.x + NF + lane + 64];
      const float wva = fmaf(w0, t0a, w1 * t1a);
      const float wvb = fmaf(w0, t0b, w1 * t1b);
      acc0 = fmaf(wva, bf2f(yu[e.y + lane]), acc0);
      acc1 = fmaf(wvb, bf2f(yu[e.y + lane + 64]), acc1);
    }
  }
  sAgg[wave][lane] = acc0;
  sAgg[wave][lane + 64] = acc1;
  __syncthreads();   // covers sAgg and sGi

  // ---- GEMM1 (W12 @ agg) + vang (awT @ Gi) into ONE accumulator ----
  f32x4 c2 = {0.f, 0.f, 0.f, 0.f};
#pragma unroll
  for (int kt = 0; kt < 4; ++kt) {
    const float* ar = &sAgg[lanelo][kt * 32 + quad * 8];
    const bf16x8 b = pack8(*(const float4*)ar, *(const float4*)(ar + 4));
    const bf16x8 a = *(const bf16x8*)(W12Tl + ((wave << 4) + lanelo) * 128 + kt * 32 + quad * 8);
    c2 = __builtin_amdgcn_mfma_f32_16x16x32_bf16(a, b, c2, 0, 0, 0);
  }
#pragma unroll 4
  for (int kt = 0; kt < 16; ++kt) {
    const int k0 = kt * 32 + quad * 8;
    const bf16x8 a = *(const bf16x8*)(awTl + (size_t)((wave << 4) + lanelo) * 512 + k0);
    const bf16x8 b = *(const bf16x8*)(&sGi[lanelo & 7][k0]);
    c2 = __builtin_amdgcn_mfma_f32_16x16x32_bf16(a, b, c2, 0, 0, 0);
  }

  const int c0 = (wave << 4) + quad * 4;
  const int row = ga0 + lanelo;
  if (lanelo < 8) {
    const float4 dv = *(const float4*)(b12l + c0);
    float* xp = x + (size_t)row * 128 + c0;
    const float4 xv = *(const float4*)xp;
    float4 xo;
    xo.x = xv.x + sspf(c2[0] + dv.x);
    xo.y = xv.y + sspf(c2[1] + dv.y);
    xo.z = xv.z + sspf(c2[2] + dv.z);
    xo.w = xv.w + sspf(c2[3] + dv.w);
    *(float4*)xp = xo;
    if (in2fTn != nullptr) {
      uint2 pk; pk.x = pk2bf(xo.x, xo.y); pk.y = pk2bf(xo.z, xo.w);
      *(uint2*)(sT + lanelo * 136 + c0) = pk;
    }
  }
  if (in2fTn == nullptr) return;
  __syncthreads();

  // ---- GEMM2: y_next = in2f[l+1] @ x_new ----
  f32x4 c3 = {0.f, 0.f, 0.f, 0.f};
#pragma unroll
  for (int kt = 0; kt < 4; ++kt) {
    const bf16x8 b = *(const bf16x8*)(sT + lanelo * 136 + kt * 32 + quad * 8);
    const bf16x8 a = *(const bf16x8*)(in2fTn + ((wave << 4) + lanelo) * 128 + kt * 32 + quad * 8);
    c3 = __builtin_amdgcn_mfma_f32_16x16x32_bf16(a, b, c3, 0, 0, 0);
  }
  if (lanelo < 8) {
    uint2 pk; pk.x = pk2bf(c3[0], c3[1]); pk.y = pk2bf(c3[2], c3[3]);
    *(uint2*)(yOut + (size_t)row * 128 + c0) = pk;
  }
}

extern "C" void kernel_launch(void* const* d_in, const int* in_sizes, int n_in,
                              void* d_out, int out_size, void* d_ws, size_t ws_size,
                              hipStream_t stream) {
  (void)in_sizes; (void)n_in; (void)out_size; (void)ws_size;
  const int* zn = (const int*)d_in[0];
  const float* pos = (const float*)d_in[1];
  const int* nbr = (const int*)d_in[2];
  const int* nmask = (const int*)d_in[3];
  const float* Gi = (const float*)d_in[4];
  const float* emb = (const float*)d_in[5];
  const float* fw1 = (const float*)d_in[6];
  const float* fb1 = (const float*)d_in[7];
  const float* fw2 = (const float*)d_in[8];
  const float* fb2 = (const float*)d_in[9];
  const float* in2f = (const float*)d_in[10];
  const float* f2o = (const float*)d_in[11];
  const float* f2ob = (const float*)d_in[12];
  const float* dwp = (const float*)d_in[13];
  const float* dbp = (const float*)d_in[14];
  const float* awp = (const float*)d_in[15];

  float* x = (float*)d_out;                              // [B,A,D] fp32
  float* b12 = (float*)d_ws;                             // [3][128] fp32
  float* Ttab = b12 + 3 * 128;                           // [3][1024][128] fp32
  short* yA = (short*)(Ttab + (size_t)3 * TABN * NF);    // y buf 0
  short* yBb = yA + (size_t)NB * NA * NF;                // y buf 1
  short* in2fT = yBb + (size_t)NB * NA * NF;             // [3][128][128]
  short* W12T = in2fT + (size_t)3 * 128 * 128;           // [3][128][128]
  short* awT = W12T + (size_t)3 * 128 * 128;             // [3][128][512]
  int4* ent = (int4*)(awT + (size_t)3 * 128 * 512);      // [B*A][64]
  int* nvArr = (int*)(ent + (size_t)NB * NA * NN);       // [B*A]

  k_prep<<<P_TOT, 256, 0, stream>>>(
      fw1, fb1, fw2, fb2, in2f, awp, f2o, f2ob, dwp, dbp,
      pos, nbr, nmask, emb, zn,
      in2fT, awT, W12T, b12, Ttab, ent, nvArr, x, yA);

  short* yin = yA;
  short* yout = yBb;
  for (int l = 0; l < 3; ++l) {
    k_layer<<<NB * NA / 8, 512, 0, stream>>>(yin,
        Ttab + (size_t)l * TABN * NF,
        Gi, awT + (size_t)l * 65536,
        x, W12T + (size_t)l * 16384, b12 + (size_t)l * 128,
        (l < 2) ? (in2fT + (size_t)(l + 1) * 16384) : nullptr, yout,
        ent, nvArr);
    short* tmp = yin; yin = yout; yout = tmp;
  }
}